// Round 15
// baseline (219.690 us; speedup 1.0000x reference)
//
#include <hip/hip_runtime.h>
#include <hip/hip_bf16.h>

typedef __bf16 bf16_t;
typedef bf16_t bf16x2 __attribute__((ext_vector_type(2)));
typedef bf16_t bf16x8 __attribute__((ext_vector_type(8)));
typedef float f32x4 __attribute__((ext_vector_type(4)));
typedef unsigned short u16;
typedef unsigned int u32;

static __device__ __forceinline__ u16 cvt1(float f) {
    return __builtin_bit_cast(u16, (bf16_t)f);
}
static __device__ __forceinline__ u32 cvt2(float a, float b) {
    bf16x2 t; t[0] = (bf16_t)a; t[1] = (bf16_t)b;
    return __builtin_bit_cast(u32, t);
}
static __device__ __forceinline__ float bf2f(u16 u) {
    u32 x = ((u32)u) << 16;
    return __builtin_bit_cast(float, x);
}
static __device__ __forceinline__ float lo32(u32 p) { return __builtin_bit_cast(float, p << 16); }
static __device__ __forceinline__ float hi32(u32 p) { return __builtin_bit_cast(float, p & 0xffff0000u); }
// soft threshold: v - clamp(v, -l, l) (fuses to v_med3)
static __device__ __forceinline__ float softthr(float v, float l, float nl) {
    return v - fmaxf(nl, fminf(v, l));
}

// trivial: Dict copy to out[2]
__global__ __launch_bounds__(256) void copy_dict(const float* __restrict__ Dict,
                                                 float* __restrict__ outd)
{
    int i = blockIdx.x * 256 + threadIdx.x;   // 65536 total
    outd[i] = Dict[i];
}

// ---- fused LISTA: rank-128 factored, dict-in-regs, split-K G1,
//      TWO 16-px tiles in ANTI-PHASE software pipeline ----
// z_{t+1} = ST( z_t + (x - z_t @ D^T) @ D / L ),  z_0 = ST(x @ D)
// Sections: S1 = G1(A) ∥ G2(B)   (LDS-read pipe ∥ MFMA pipe, kt-fused)
//           S2 = RED(A) ∥ G1(B)  (VALU ∥ LDS-read)
//           S3 = G2(A) ∥ RED(B)
// Per-tile numerics identical to the 207-210µs champions (fp32 persistent z).
__global__ __launch_bounds__(512, 2)
void lista_main(const float* __restrict__ x,
                const float* __restrict__ Dict,    // fp32 [128][512]
                const float* __restrict__ alpha,
                const float* __restrict__ Lp,
                const int* __restrict__ nip,
                float* __restrict__ outz,          // [32][512][1024]
                float* __restrict__ outr)          // [32][128][1024]
{
    __shared__ __align__(16) u16 zlA[16 * 512], zlB[16 * 512];   // 2x16KB z bf16 [px][atom]
    __shared__ __align__(16) u16 rlA[16 * 128], rlB[16 * 128];   // 2x4KB  r bf16 [px][dim]
    __shared__ __align__(16) u16 xsA[16 * 128], xsB[16 * 128];   // 2x4KB  x bf16 [px][dim]
    __shared__ __align__(16) u16 pbA[16 * 512], pbB[16 * 512];   // 2x16KB partials [px][ag][dim]

    const int t = threadIdx.x;
    const int lane = t & 63;
    const int l15 = lane & 15;           // px within tile / fragment row
    const int lg = lane >> 4;            // 0..3
    const int wave = t >> 6;             // 0..7
    const int dg = wave >> 2;            // 0..1 : G1 dim-group (64 dims)
    const int ag = wave & 3;             // 0..3 : G1 atom-group (128 atoms)
    const int atb = wave << 6;           // G2 atom base (64 atoms/wave)
    const int bb = blockIdx.x >> 5;             // batch
    const int hw0 = (blockIdx.x & 31) << 5;     // 32-pixel base (2 tiles of 16)
    const float invL = 1.0f / Lp[0];
    const int niter = nip[0];
    const int sw0 = (l15 & 7) << 3;

    // ---- stage xs = bf16(x) [px][dim] swizzled, both tiles ----
    for (int i = t; i < 2 * 16 * 128; i += 512) {
        int tt = i >> 11, j = i & 2047;
        int d = j >> 4, px = j & 15;
        u16* xst = tt ? xsB : xsA;
        xst[((px << 7) + d) ^ ((px & 7) << 3)] =
            cvt1(x[((bb * 128 + d) << 10) + hw0 + tt * 16 + px]);
    }

    const float thrA = alpha[hw0 + l15] * invL,      nthrA = -thrA;
    const float thrB = alpha[hw0 + 16 + l15] * invL, nthrB = -thrB;

    // ---- dict fragments -> registers (once) ----
    // G1 A: -D[dg*64+mt*16+l15][ag*128+kt*32+lg*8+j]  (row-contiguous)
    bf16x8 g1a[4][4];
#pragma unroll
    for (int mt = 0; mt < 4; ++mt) {
        const float* drow = Dict + ((dg * 64 + mt * 16 + l15) << 9) + ag * 128 + lg * 8;
#pragma unroll
        for (int kt = 0; kt < 4; ++kt) {
            f32x4 c0 = *reinterpret_cast<const f32x4*>(drow + kt * 32);
            f32x4 c1 = *reinterpret_cast<const f32x4*>(drow + kt * 32 + 4);
#pragma unroll
            for (int j = 0; j < 4; ++j) {
                g1a[mt][kt][j] = (bf16_t)(-c0[j]);
                g1a[mt][kt][j + 4] = (bf16_t)(-c1[j]);
            }
        }
    }
    // G2 A: D^T[atb+at*16+l15][kt*32+lg*8+j] (column gather, once)
    bf16x8 g2a[4][4];
#pragma unroll
    for (int at = 0; at < 4; ++at)
#pragma unroll
        for (int kt = 0; kt < 4; ++kt)
#pragma unroll
            for (int j = 0; j < 8; ++j)
                g2a[at][kt][j] = (bf16_t)(Dict[((kt * 32 + lg * 8 + j) << 9) + atb + at * 16 + l15]);

    __syncthreads();

    // ---- per-tile op lambdas ----
    // G2 alone: acc += D^T @ bsrc^T; ST; write z bf16 to zlt
    auto g2_tile = [&](f32x4 (&acc)[4], u16* zlt, const u16* bsrc,
                       float thv, float nthv) {
#pragma unroll
        for (int kt = 0; kt < 4; ++kt) {
            bf16x8 Bf = *reinterpret_cast<const bf16x8*>(
                &bsrc[((l15 << 7) + kt * 32 + lg * 8) ^ sw0]);
#pragma unroll
            for (int at = 0; at < 4; ++at)
                acc[at] = __builtin_amdgcn_mfma_f32_16x16x32_bf16(
                    g2a[at][kt], Bf, acc[at], 0, 0, 0);
        }
#pragma unroll
        for (int at = 0; at < 4; ++at) {
            f32x4 a = acc[at];
            a[0] = softthr(a[0], thv, nthv);
            a[1] = softthr(a[1], thv, nthv);
            a[2] = softthr(a[2], thv, nthv);
            a[3] = softthr(a[3], thv, nthv);
            acc[at] = a;
            uint2 pk;
            pk.x = cvt2(a[0], a[1]);
            pk.y = cvt2(a[2], a[3]);
            *reinterpret_cast<uint2*>(
                &zlt[((l15 << 9) + atb + at * 16 + lg * 4) ^ sw0]) = pk;
        }
    };

    // G1 alone: partial over ag's 128 atoms -> pbt
    auto g1_tile = [&](const u16* zlt, u16* pbt) {
        f32x4 a1p[4];
#pragma unroll
        for (int mt = 0; mt < 4; ++mt)
            a1p[mt] = f32x4{0.f, 0.f, 0.f, 0.f};
#pragma unroll
        for (int kt = 0; kt < 4; ++kt) {
            bf16x8 Bf = *reinterpret_cast<const bf16x8*>(
                &zlt[((l15 << 9) + ag * 128 + kt * 32 + lg * 8) ^ sw0]);
#pragma unroll
            for (int mt = 0; mt < 4; ++mt)
                a1p[mt] = __builtin_amdgcn_mfma_f32_16x16x32_bf16(
                    g1a[mt][kt], Bf, a1p[mt], 0, 0, 0);
        }
#pragma unroll
        for (int mt = 0; mt < 4; ++mt) {
            int d0 = dg * 64 + mt * 16 + lg * 4;
            uint2 pk;
            pk.x = cvt2(a1p[mt][0], a1p[mt][1]);
            pk.y = cvt2(a1p[mt][2], a1p[mt][3]);
            *reinterpret_cast<uint2*>(
                &pbt[((l15 << 9) + (ag << 7) + d0) ^ sw0]) = pk;
        }
    };

    // FUSED G1(t1) ∥ G2(t2): kt-interleaved so LDS-read and MFMA chains overlap
    auto g1_g2 = [&](const u16* zl_r, u16* pb_w,
                     f32x4 (&acc)[4], u16* zl_w, const u16* bsrc,
                     float thv, float nthv) {
        f32x4 a1p[4];
#pragma unroll
        for (int mt = 0; mt < 4; ++mt)
            a1p[mt] = f32x4{0.f, 0.f, 0.f, 0.f};
#pragma unroll
        for (int kt = 0; kt < 4; ++kt) {
            bf16x8 Bf1 = *reinterpret_cast<const bf16x8*>(
                &zl_r[((l15 << 9) + ag * 128 + kt * 32 + lg * 8) ^ sw0]);
            bf16x8 Bf2 = *reinterpret_cast<const bf16x8*>(
                &bsrc[((l15 << 7) + kt * 32 + lg * 8) ^ sw0]);
#pragma unroll
            for (int mt = 0; mt < 4; ++mt)
                a1p[mt] = __builtin_amdgcn_mfma_f32_16x16x32_bf16(
                    g1a[mt][kt], Bf1, a1p[mt], 0, 0, 0);
#pragma unroll
            for (int at = 0; at < 4; ++at)
                acc[at] = __builtin_amdgcn_mfma_f32_16x16x32_bf16(
                    g2a[at][kt], Bf2, acc[at], 0, 0, 0);
        }
#pragma unroll
        for (int mt = 0; mt < 4; ++mt) {
            int d0 = dg * 64 + mt * 16 + lg * 4;
            uint2 pk;
            pk.x = cvt2(a1p[mt][0], a1p[mt][1]);
            pk.y = cvt2(a1p[mt][2], a1p[mt][3]);
            *reinterpret_cast<uint2*>(
                &pb_w[((l15 << 9) + (ag << 7) + d0) ^ sw0]) = pk;
        }
#pragma unroll
        for (int at = 0; at < 4; ++at) {
            f32x4 a = acc[at];
            a[0] = softthr(a[0], thv, nthv);
            a[1] = softthr(a[1], thv, nthv);
            a[2] = softthr(a[2], thv, nthv);
            a[3] = softthr(a[3], thv, nthv);
            acc[at] = a;
            uint2 pk;
            pk.x = cvt2(a[0], a[1]);
            pk.y = cvt2(a[2], a[3]);
            *reinterpret_cast<uint2*>(
                &zl_w[((l15 << 9) + atb + at * 16 + lg * 4) ^ sw0]) = pk;
        }
    };

    // reduce one tile with all 512 threads: r = (x + Σ partials) * invL
    auto reduce_tile = [&](const u16* pbt, const u16* xst, u16* rlt) {
        const int px = t >> 5;
        const int d0 = (t & 31) << 2;
        const int sw = (px & 7) << 3;
        uint2 P0 = *reinterpret_cast<const uint2*>(&pbt[((px << 9) + 0 * 128 + d0) ^ sw]);
        uint2 P1 = *reinterpret_cast<const uint2*>(&pbt[((px << 9) + 1 * 128 + d0) ^ sw]);
        uint2 P2 = *reinterpret_cast<const uint2*>(&pbt[((px << 9) + 2 * 128 + d0) ^ sw]);
        uint2 P3 = *reinterpret_cast<const uint2*>(&pbt[((px << 9) + 3 * 128 + d0) ^ sw]);
        uint2 XV = *reinterpret_cast<const uint2*>(&xst[((px << 7) + d0) ^ sw]);
        float s0 = (lo32(XV.x) + lo32(P0.x)) + (lo32(P1.x) + lo32(P2.x)) + lo32(P3.x);
        float s1 = (hi32(XV.x) + hi32(P0.x)) + (hi32(P1.x) + hi32(P2.x)) + hi32(P3.x);
        float s2 = (lo32(XV.y) + lo32(P0.y)) + (lo32(P1.y) + lo32(P2.y)) + lo32(P3.y);
        float s3 = (hi32(XV.y) + hi32(P0.y)) + (hi32(P1.y) + hi32(P2.y)) + hi32(P3.y);
        uint2 rv;
        rv.x = cvt2(s0 * invL, s1 * invL);
        rv.y = cvt2(s2 * invL, s3 * invL);
        *reinterpret_cast<uint2*>(&rlt[((px << 7) + d0) ^ sw]) = rv;
    };

    f32x4 acczA[4], acczB[4];
#pragma unroll
    for (int at = 0; at < 4; ++at) {
        acczA[at] = f32x4{0.f, 0.f, 0.f, 0.f};
        acczB[at] = f32x4{0.f, 0.f, 0.f, 0.f};
    }

    // ---- anti-phase pipeline ----
    // P1: G2(A,0)
    g2_tile(acczA, zlA, xsA, thrA, nthrA);
    __syncthreads();
    // S1(1): G1(A,1) ∥ G2(B,0)
    g1_g2(zlA, pbA, acczB, zlB, xsB, thrB, nthrB);
    __syncthreads();

    for (int k = 1; k <= niter; ++k) {
        // S2: RED(A,k) ∥ G1(B,k)
        reduce_tile(pbA, xsA, rlA);
        g1_tile(zlB, pbB);
        __syncthreads();
        // S3: G2(A,k) ∥ RED(B,k)
        g2_tile(acczA, zlA, rlA, thrA, nthrA);
        reduce_tile(pbB, xsB, rlB);
        __syncthreads();
        // S1(k+1): G1(A,k+1) ∥ G2(B,k)   [k=niter: G1(A) = final partials]
        g1_g2(zlA, pbA, acczB, zlB, rlB, thrB, nthrB);
        __syncthreads();
    }

    // E1: G1(B,final) ∥ rec(A) from pbA
    float recA[4];
    {
        const int px = t >> 5;
        const int d0 = (t & 31) << 2;
        const int sw = (px & 7) << 3;
        uint2 P0 = *reinterpret_cast<const uint2*>(&pbA[((px << 9) + 0 * 128 + d0) ^ sw]);
        uint2 P1 = *reinterpret_cast<const uint2*>(&pbA[((px << 9) + 1 * 128 + d0) ^ sw]);
        uint2 P2 = *reinterpret_cast<const uint2*>(&pbA[((px << 9) + 2 * 128 + d0) ^ sw]);
        uint2 P3 = *reinterpret_cast<const uint2*>(&pbA[((px << 9) + 3 * 128 + d0) ^ sw]);
        recA[0] = -((lo32(P0.x) + lo32(P1.x)) + (lo32(P2.x) + lo32(P3.x)));
        recA[1] = -((hi32(P0.x) + hi32(P1.x)) + (hi32(P2.x) + hi32(P3.x)));
        recA[2] = -((lo32(P0.y) + lo32(P1.y)) + (lo32(P2.y) + lo32(P3.y)));
        recA[3] = -((hi32(P0.y) + hi32(P1.y)) + (hi32(P2.y) + hi32(P3.y)));
    }
    g1_tile(zlB, pbB);
    __syncthreads();

    // E2: rec(B) from pbB
    float recB[4];
    {
        const int px = t >> 5;
        const int d0 = (t & 31) << 2;
        const int sw = (px & 7) << 3;
        uint2 P0 = *reinterpret_cast<const uint2*>(&pbB[((px << 9) + 0 * 128 + d0) ^ sw]);
        uint2 P1 = *reinterpret_cast<const uint2*>(&pbB[((px << 9) + 1 * 128 + d0) ^ sw]);
        uint2 P2 = *reinterpret_cast<const uint2*>(&pbB[((px << 9) + 2 * 128 + d0) ^ sw]);
        uint2 P3 = *reinterpret_cast<const uint2*>(&pbB[((px << 9) + 3 * 128 + d0) ^ sw]);
        recB[0] = -((lo32(P0.x) + lo32(P1.x)) + (lo32(P2.x) + lo32(P3.x)));
        recB[1] = -((hi32(P0.x) + hi32(P1.x)) + (hi32(P2.x) + hi32(P3.x)));
        recB[2] = -((lo32(P0.y) + lo32(P1.y)) + (lo32(P2.y) + lo32(P3.y)));
        recB[3] = -((hi32(P0.y) + hi32(P1.y)) + (hi32(P2.y) + hi32(P3.y)));
    }

    // ---- store z from zlA/zlB (nontemporal) ----
    for (int i = t; i < 2 * 16 * 512; i += 512) {
        int tt = i >> 13, j = i & 8191;
        int a = j >> 4, px = j & 15;
        const u16* zlt = tt ? zlB : zlA;
        float zv = bf2f(zlt[((px << 9) + a) ^ ((px & 7) << 3)]);
        __builtin_nontemporal_store(zv, &outz[((bb * 512 + a) << 10) + hw0 + tt * 16 + px]);
    }
    __syncthreads();   // rec extracted; safe to overwrite pb as fp32

    // ---- stage recon fp32 [px][dim] swizzled into pbA/pbB regions ----
    {
        const int px = t >> 5;
        const int d0 = (t & 31) << 2;
        const int swf = (px & 7) << 2;
        float* wfA = reinterpret_cast<float*>(pbA);
        float* wfB = reinterpret_cast<float*>(pbB);
        f32x4 va{recA[0], recA[1], recA[2], recA[3]};
        f32x4 vb{recB[0], recB[1], recB[2], recB[3]};
        *reinterpret_cast<f32x4*>(&wfA[((px << 7) + d0) ^ swf]) = va;
        *reinterpret_cast<f32x4*>(&wfB[((px << 7) + d0) ^ swf]) = vb;
    }
    __syncthreads();

    // ---- store x_recon (nontemporal) ----
    for (int i = t; i < 2 * 16 * 128; i += 512) {
        int tt = i >> 11, j = i & 2047;
        int d = j >> 4, px = j & 15;
        const float* wf = reinterpret_cast<const float*>(tt ? pbB : pbA);
        __builtin_nontemporal_store(wf[((px << 7) + d) ^ ((px & 7) << 2)],
                                    &outr[((bb * 128 + d) << 10) + hw0 + tt * 16 + px]);
    }
}

extern "C" void kernel_launch(void* const* d_in, const int* in_sizes, int n_in,
                              void* d_out, int out_size, void* d_ws, size_t ws_size,
                              hipStream_t stream)
{
    const float* x     = (const float*)d_in[0];
    const float* Dict  = (const float*)d_in[1];
    const float* alpha = (const float*)d_in[2];
    const float* Lp    = (const float*)d_in[3];
    const int*   nip   = (const int*)d_in[4];

    float* outz = (float*)d_out;                 // [32,512,32,32]
    float* outr = outz + 32 * 512 * 1024;        // [32,128,32,32]
    float* outd = outr + 32 * 128 * 1024;        // [128,512]

    copy_dict<<<dim3(256), dim3(256), 0, stream>>>(Dict, outd);
    lista_main<<<dim3(1024), dim3(512), 0, stream>>>(x, Dict, alpha, Lp, nip,
                                                     outz, outr);
}